// Round 3
// baseline (229.070 us; speedup 1.0000x reference)
//
#include <hip/hip_runtime.h>

// FWHT over last dim (n = 4096), normalized by 1/64. One block (256 thr) per row.
// Structure (R3): DMA row global->LDS via global_load_lds (width 16), then three
// all-LDS register phases of 4 butterfly bits each (butterflies commute):
//   P1: bits {6..9}   (32 scalar b32 LDS ops, 2-way banks = free)
//   P2: bits {2..5}   (32 scalar b32 LDS ops, verified 32-banks/wave = free)
//   P3: bits {0,1,10,11} (4x ds_read_b128, compute in regs, nt global_store_dwordx4)
// LDS layout L(A) = A ^ (((A>>8)&7)<<2) on dword addrs (fixed bijection ->
// correctness-neutral). Bits 8..10 are uniform per DMA chunk (issue j, wave w),
// so L is produced by lane-XOR-permuting the *global fetch* address (stays within
// the same 1 KB segment -> fully coalesced); the forced uniform+lane*16 LDS dest
// then lands each element exactly at L(elem). Verified:
//   DMA chunk (j,w): K = j | ((w&1)<<2); lane l fetches f4 (l^K) + 64j + 256w,
//     writes LDS f4 l + 64j + 256w  =>  phys L(A) holds element A.
//   P1 (elem = l + 64r + 1024w): phys = (l ^ ((r>>2)<<2) ^ ((w&1)<<4)) + 64r + 1024w
//     -> bank = (l^const)&31 per instr -> 2-way, free. Thread r/w same set.
//   P2 (elem = (t&3) | r<<2 | ((t>>5)&3)<<6 | ((t>>2)&7)<<8 | (t>>7)<<11):
//     phys = base2 + 4*(r ^ s2), s2 = (t>>2)&7 -> bank = (l&3) | ((r^(l>>2))&7)<<2
//     -> 32 distinct banks, 2 lanes each -> free. Thread r/w same set.
//   P3 (elem f4 = t + 256j): phys f4 = (t ^ ((t>>6)&3) ^ ((j&1)<<2)) + 256j
//     -> XOR-permutation of canonical b128 pattern -> conflict-free.

using v4 = __attribute__((ext_vector_type(4))) float;

__device__ __forceinline__ void had16(float x[16]) {
#pragma unroll
    for (int h = 1; h < 16; h <<= 1) {
#pragma unroll
        for (int i = 0; i < 16; ++i) {
            if (!(i & h)) {
                float a = x[i], b = x[i ^ h];
                x[i] = a + b; x[i ^ h] = a - b;
            }
        }
    }
}

__global__ void __launch_bounds__(256) fwht4096_kernel(const float* __restrict__ in,
                                                       float* __restrict__ out) {
    __shared__ float lds[4096];
    const int t = threadIdx.x;
    const int l = t & 63, w = t >> 6;
    const size_t base = (size_t)blockIdx.x * 4096;

    // ---------------- Stage A: DMA global -> LDS (layout L) ----------------
#pragma unroll
    for (int j = 0; j < 4; ++j) {
        const int K = j | ((w & 1) << 2);
        const float* gp = in + base + 4 * ((l ^ K) + 64 * j + 256 * w);
        float* lp = lds + 4 * l + 256 * j + 1024 * w;
        __builtin_amdgcn_global_load_lds(
            (const __attribute__((address_space(1))) void*)gp,
            (__attribute__((address_space(3))) void*)lp, 16, 0, 0);
    }
    __syncthreads();

    float x[16];

    // ---------------- P1: bits {6..9} ----------------
    {
        const int b1 = 1024 * w;
        const int wx = (w & 1) << 4;
#pragma unroll
        for (int r = 0; r < 16; ++r)
            x[r] = lds[(l ^ ((r >> 2) << 2) ^ wx) + 64 * r + b1];
        had16(x);
#pragma unroll
        for (int r = 0; r < 16; ++r)
            lds[(l ^ ((r >> 2) << 2) ^ wx) + 64 * r + b1] = x[r];
    }
    __syncthreads();

    // ---------------- P2: bits {2..5} ----------------
    {
        const int s2 = (t >> 2) & 7;
        const int base2 = (t & 3) | (((t >> 5) & 3) << 6) | (s2 << 8) | ((t >> 7) << 11);
#pragma unroll
        for (int r = 0; r < 16; ++r) x[r] = lds[base2 + 4 * (r ^ s2)];
        had16(x);
#pragma unroll
        for (int r = 0; r < 16; ++r) lds[base2 + 4 * (r ^ s2)] = x[r];
    }
    __syncthreads();

    // ---------------- P3: bits {0,1,10,11} + direct vectorized store ----------------
    {
        const v4* l4 = reinterpret_cast<const v4*>(lds);
        v4* out4 = reinterpret_cast<v4*>(out + base);
        const int k3 = (t >> 6) & 3;
#pragma unroll
        for (int j = 0; j < 4; ++j) {
            v4 vv = l4[(t ^ k3 ^ ((j & 1) << 2)) + 256 * j];
#pragma unroll
            for (int e = 0; e < 4; ++e) x[e + 4 * j] = vv[e];
        }
        had16(x);  // index = e + 4*j  <->  elem bits {0,1} = e, {10,11} = j
        const float scale = 0.015625f;  // 1/64 = 1/sqrt(4096), exact
#pragma unroll
        for (int j = 0; j < 4; ++j) {
            v4 o;
#pragma unroll
            for (int e = 0; e < 4; ++e) o[e] = x[e + 4 * j] * scale;
            __builtin_nontemporal_store(o, &out4[t + 256 * j]);
        }
    }
}

extern "C" void kernel_launch(void* const* d_in, const int* in_sizes, int n_in,
                              void* d_out, int out_size, void* d_ws, size_t ws_size,
                              hipStream_t stream) {
    const float* x = (const float*)d_in[0];
    float* out = (float*)d_out;
    const int rows = in_sizes[0] >> 12;  // / 4096
    fwht4096_kernel<<<dim3(rows), dim3(256), 0, stream>>>(x, out);
}

// Round 4
// 221.609 us; speedup vs baseline: 1.0337x; 1.0337x over previous
//
#include <hip/hip_runtime.h>

// FWHT over last dim (n = 4096), normalized by 1/64.
// R4: persistent-style — 2048 blocks x 4 rows/block, explicit register prefetch
// of row r+1's global loads issued before row r's LDS phases (overlap HBM with
// DS/VALU). Per-row body = R2's verified structure:
//   P1: bits {0,1,10,11} in regs from float4 global loads
//   P2: bits {2..5}  LDS exchange (scalar b32, 32 banks/wave -> free)
//   P3: bits {6..9}  LDS exchange + 1/64 scale
//   Gather: conflict-free ds_read_b128 + nt global_store_dwordx4
// LDS swizzle S(A) = A ^ (((A>>6)&7)<<2) on dword addrs (fixed bijection).
// Bank math (verified R2): P1 write/gather read b128 conflict-free; P2/P3 2-way
// max = free (m136).

using v4 = __attribute__((ext_vector_type(4))) float;

__device__ __forceinline__ void had16(float x[16]) {
#pragma unroll
    for (int h = 1; h < 16; h <<= 1) {
#pragma unroll
        for (int i = 0; i < 16; ++i) {
            if (!(i & h)) {
                float a = x[i], b = x[i ^ h];
                x[i] = a + b; x[i ^ h] = a - b;
            }
        }
    }
}

#define ROWS_PER_BLOCK 4

__global__ void __launch_bounds__(256) fwht4096_kernel(const float* __restrict__ in,
                                                       float* __restrict__ out) {
    __shared__ float lds[4096];
    const int t = threadIdx.x;
    const size_t row0 = (size_t)blockIdx.x * ROWS_PER_BLOCK;

    // Preload row 0 of this block.
    v4 cur[4];
    {
        const v4* in4 = reinterpret_cast<const v4*>(in + row0 * 4096);
#pragma unroll
        for (int j = 0; j < 4; ++j) cur[j] = __builtin_nontemporal_load(&in4[t + 256 * j]);
    }

#pragma unroll
    for (int r = 0; r < ROWS_PER_BLOCK; ++r) {
        const size_t base = (row0 + r) * 4096;

        // ---- P1: bits {0,1,10,11} in registers ----
#pragma unroll
        for (int j = 0; j < 4; ++j) {  // bits 0,1 (within float4)
            float a = cur[j][0], b = cur[j][1], c = cur[j][2], d = cur[j][3];
            float ab = a + b, amb = a - b, cd = c + d, cmd = c - d;
            cur[j][0] = ab + cd; cur[j][1] = amb + cmd;
            cur[j][2] = ab - cd; cur[j][3] = amb - cmd;
        }
        {  // bits 10,11 (across j)
            v4 s0 = cur[0] + cur[1], d0 = cur[0] - cur[1];
            v4 s1 = cur[2] + cur[3], d1 = cur[2] - cur[3];
            cur[0] = s0 + s1; cur[2] = s0 - s1;
            cur[1] = d0 + d1; cur[3] = d0 - d1;
        }

        if (r > 0) __syncthreads();  // previous row's gather reads must finish

        {  // LDS write at S(4t + 1024j): float4 idx (t ^ ((t>>4)&7)) + 256j
            v4* l4 = reinterpret_cast<v4*>(lds);
            const int wb = t ^ ((t >> 4) & 7);
#pragma unroll
            for (int j = 0; j < 4; ++j) l4[wb + 256 * j] = cur[j];
        }

        // ---- Prefetch next row into registers (in flight across barriers) ----
        v4 nxt[4];
        if (r + 1 < ROWS_PER_BLOCK) {
            const v4* in4n = reinterpret_cast<const v4*>(in + (row0 + r + 1) * 4096);
#pragma unroll
            for (int j = 0; j < 4; ++j) nxt[j] = __builtin_nontemporal_load(&in4n[t + 256 * j]);
        }
        __syncthreads();

        float x[16];

        // ---- P2: bits {2..5} ----
        {
            const int b2 = (t & 3) + 64 * (t >> 2);
            const int s2 = (t >> 2) & 7;
#pragma unroll
            for (int q = 0; q < 16; ++q) x[q] = lds[b2 + 4 * (q ^ s2)];
            had16(x);
#pragma unroll
            for (int q = 0; q < 16; ++q) lds[b2 + 4 * (q ^ s2)] = x[q];
        }
        __syncthreads();

        // ---- P3: bits {6..9} + 1/64 scale ----
        {
            const int l = t & 63, w = t >> 6;
            const int b3 = 1024 * w;
#pragma unroll
            for (int q = 0; q < 16; ++q) x[q] = lds[(l ^ ((q & 7) << 2)) + 64 * q + b3];
            had16(x);
            const float scale = 0.015625f;  // 1/64 = 1/sqrt(4096), exact
#pragma unroll
            for (int q = 0; q < 16; ++q)
                lds[(l ^ ((q & 7) << 2)) + 64 * q + b3] = x[q] * scale;
        }
        __syncthreads();

        // ---- Gather + vectorized nontemporal store ----
        {
            const v4* l4 = reinterpret_cast<const v4*>(lds);
            v4* out4 = reinterpret_cast<v4*>(out + base);
            const int wb = t ^ ((t >> 4) & 7);
#pragma unroll
            for (int j = 0; j < 4; ++j) {
                v4 o = l4[wb + 256 * j];
                __builtin_nontemporal_store(o, &out4[t + 256 * j]);
            }
        }

#pragma unroll
        for (int j = 0; j < 4; ++j) cur[j] = nxt[j];
    }
}

extern "C" void kernel_launch(void* const* d_in, const int* in_sizes, int n_in,
                              void* d_out, int out_size, void* d_ws, size_t ws_size,
                              hipStream_t stream) {
    const float* x = (const float*)d_in[0];
    float* out = (float*)d_out;
    const int rows = in_sizes[0] >> 12;  // / 4096
    fwht4096_kernel<<<dim3(rows / ROWS_PER_BLOCK), dim3(256), 0, stream>>>(x, out);
}

// Round 5
// 219.228 us; speedup vs baseline: 1.0449x; 1.0109x over previous
//
#include <hip/hip_runtime.h>

// FWHT over last dim (n = 4096), normalized by 1/64.
// R5: one 64-thread (single-wave) block per row; 64 elems/thread in 16 v4 regs;
// three 4-bit butterfly phases, ALL LDS traffic as ds_read/write_b128:
//   A: elem bits {0,1,10,11}  (f4 components e + reg-index bits {2,3})
//   B: elem bits {2..5}       (had16 over k, v4 payload)
//   C: elem bits {6..9}       (had16 over q, v4 payload) + 1/64 + nt store
// f4 index f = elem>>2 (10 bits). Global LDS swizzle P(f) = f ^ ((f>>4)&15)
// (fixed bijection -> correctness-neutral). Verified conflict-free per phase
// (per 16-lane group, phys low-4 bits take 16 distinct values -> each bank-quad
// hit exactly 2x = canonical b128 pattern):
//   A write (f=l+64j):            phys = f ^ ((l>>4)&3) ^ ((j&3)<<2)
//   B r/w   (f=k+16l):            phys = 16l + (k ^ (l&15))
//   C read  (f=(l&15)|(q<<4)|((l>>4)<<8)): phys = f ^ q  (bits 0..3)
// Barriers are single-wave (trivial). Store instr q covers 4 x 256B contiguous
// segments (full line utilization).

using v4 = __attribute__((ext_vector_type(4))) float;

__device__ __forceinline__ void had16v(v4 x[16]) {
#pragma unroll
    for (int h = 1; h < 16; h <<= 1) {
#pragma unroll
        for (int i = 0; i < 16; ++i) {
            if (!(i & h)) {
                v4 a = x[i], b = x[i ^ h];
                x[i] = a + b; x[i ^ h] = a - b;
            }
        }
    }
}

__global__ void __launch_bounds__(64) fwht4096_kernel(const float* __restrict__ in,
                                                      float* __restrict__ out) {
    __shared__ v4 lds[1024];  // 16 KiB, f4-indexed through P
    const int l = threadIdx.x;  // 0..63
    const size_t base = (size_t)blockIdx.x * 1024;  // in f4 units
    const v4* in4 = reinterpret_cast<const v4*>(in) + base;
    v4* out4 = reinterpret_cast<v4*>(out) + base;

    // ---- A: load (canonical coalesced) + butterfly bits {0,1,10,11} ----
    v4 r[16];
#pragma unroll
    for (int j = 0; j < 16; ++j) r[j] = __builtin_nontemporal_load(&in4[l + 64 * j]);

    // elem bits {10,11} = f bits {8,9} = j bits {2,3}: had4 across j-stride-4
#pragma unroll
    for (int jl = 0; jl < 4; ++jl) {
        v4 s0 = r[jl] + r[jl + 4], d0 = r[jl] - r[jl + 4];
        v4 s1 = r[jl + 8] + r[jl + 12], d1 = r[jl + 8] - r[jl + 12];
        r[jl] = s0 + s1; r[jl + 8] = s0 - s1;
        r[jl + 4] = d0 + d1; r[jl + 12] = d0 - d1;
    }
    // elem bits {0,1}: had4 within the float4 components
#pragma unroll
    for (int j = 0; j < 16; ++j) {
        float a = r[j][0], b = r[j][1], c = r[j][2], d = r[j][3];
        float ab = a + b, amb = a - b, cd = c + d, cmd = c - d;
        r[j][0] = ab + cd; r[j][1] = amb + cmd;
        r[j][2] = ab - cd; r[j][3] = amb - cmd;
    }
    {
        const int sA = (l >> 4) & 3;
#pragma unroll
        for (int j = 0; j < 16; ++j)
            lds[(l + 64 * j) ^ sA ^ ((j & 3) << 2)] = r[j];
    }
    __syncthreads();

    // ---- B: butterfly elem bits {2..5} (f = k + 16l) ----
    {
        const int sB = l & 15;
#pragma unroll
        for (int k = 0; k < 16; ++k) r[k] = lds[16 * l + (k ^ sB)];
        had16v(r);
#pragma unroll
        for (int k = 0; k < 16; ++k) lds[16 * l + (k ^ sB)] = r[k];
    }
    __syncthreads();

    // ---- C: butterfly elem bits {6..9} + scale + store ----
    {
        const int lo = l & 15, hi = (l >> 4) << 8;
#pragma unroll
        for (int q = 0; q < 16; ++q) r[q] = lds[(lo ^ q) | (q << 4) | hi];
        had16v(r);
        const float scale = 0.015625f;  // 1/64 = 1/sqrt(4096), exact
#pragma unroll
        for (int q = 0; q < 16; ++q) {
            v4 o = r[q] * scale;
            __builtin_nontemporal_store(o, &out4[lo | (q << 4) | hi]);
        }
    }
}

extern "C" void kernel_launch(void* const* d_in, const int* in_sizes, int n_in,
                              void* d_out, int out_size, void* d_ws, size_t ws_size,
                              hipStream_t stream) {
    const float* x = (const float*)d_in[0];
    float* out = (float*)d_out;
    const int rows = in_sizes[0] >> 12;  // / 4096
    fwht4096_kernel<<<dim3(rows), dim3(64), 0, stream>>>(x, out);
}